// Round 9
// baseline (222.144 us; speedup 1.0000x reference)
//
#include <hip/hip_runtime.h>

typedef unsigned short u16;
typedef unsigned int u32;
typedef __attribute__((ext_vector_type(8))) short bf16x8;
typedef __attribute__((ext_vector_type(4))) float f32x4;
typedef __attribute__((ext_vector_type(16))) float f32x16;
typedef __attribute__((ext_vector_type(2))) unsigned int u32x2;  // clang-native for NT builtins

#define MFMA16 __builtin_amdgcn_mfma_f32_16x16x32_bf16
#define MFMA32 __builtin_amdgcn_mfma_f32_32x32x16_bf16

__device__ __forceinline__ u16 f2bf(float f) {
  u32 u = __builtin_bit_cast(u32, f);
  u = u + 0x7FFFu + ((u >> 16) & 1u);
  return (u16)(u >> 16);
}
__device__ __forceinline__ u32 pk2(float lo, float hi) {
  return (u32)f2bf(lo) | ((u32)f2bf(hi) << 16);
}
__device__ __forceinline__ float bf2f(u32 x) {
  return __builtin_bit_cast(float, x << 16);
}
__device__ __forceinline__ u32 cvtpk(float lo, float hi) {
  u32 r;
  asm("v_cvt_pk_bf16_f32 %0, %1, %2" : "=v"(r) : "v"(lo), "v"(hi));
  return r;
}
// v_permlane32_swap_b32 a, b : new a = {a.lo, b.lo}, new b = {a.hi, b.hi}
// ONLY safe with genuinely distinct source registers (R5-proven in repack).
// R6 LESSON: using it on two copies of one value to emulate shfl_xor(32) broke.
__device__ __forceinline__ void pswap(u32& x, u32& y) {
  asm("v_permlane32_swap_b32 %0, %1" : "+v"(x), "+v"(y));
}
__device__ __forceinline__ void gld16(const void* gp, void* lp) {
  __builtin_amdgcn_global_load_lds((const __attribute__((address_space(1))) u32*)gp,
                                   (__attribute__((address_space(3))) u32*)lp, 16, 0, 0);
}

// ---------------- kernel 0: fp32 -> bf16 convert (x, Wq|Wk|Wv) ----------------
__global__ __launch_bounds__(256) void cvt_kernel(
    const float* __restrict__ x, const float* __restrict__ wq,
    const float* __restrict__ wk, const float* __restrict__ wv,
    u16* __restrict__ xbf, u16* __restrict__ wbf) {
  int idx = blockIdx.x * 256 + threadIdx.x;
  if (idx < 1048576) {
    float4 v = ((const float4*)x)[idx];
    uint2 u; u.x = pk2(v.x, v.y); u.y = pk2(v.z, v.w);
    ((uint2*)xbf)[idx] = u;
  } else {
    int j = idx - 1048576;
    const float* W = (j < 16384) ? wq : (j < 32768) ? wk : wv;
    int k = j & 16383;
    float4 v = ((const float4*)W)[k];
    uint2 u; u.x = pk2(v.x, v.y); u.y = pk2(v.z, v.w);
    ((uint2*)wbf)[j] = u;
  }
}

// ---------------- kernel 1: QKV projection ----------------
// mat 0: Qs[s][e] = (x @ Wq^T) * (log2(e)/16)
// mat 1: Ks[s][e] =  x @ Wk^T
// mat 2: Vt[e][s] =  (x @ Wv^T)^T
__global__ __launch_bounds__(256, 2) void proj_kernel(
    const u16* __restrict__ xbf, const u16* __restrict__ wbf,
    u16* __restrict__ Qs, u16* __restrict__ Ks, u16* __restrict__ Vt) {
  int tile = blockIdx.x, mat = blockIdx.y;
  int tid = threadIdx.x, w = tid >> 6, lane = tid & 63, b15 = lane & 15, g = lane >> 4;
  int base = tile * 64 + w * 16;
  const u16* W = wbf + mat * 65536;
  const u16* Xp = xbf + (size_t)(base + b15) * 256;
  f32x4 acc[16] = {};
  if (mat < 2) {
#pragma unroll
    for (int kk = 0; kk < 8; ++kk) {
      bf16x8 xf = *(const bf16x8*)(Xp + kk * 32 + g * 8);
#pragma unroll
      for (int eb = 0; eb < 16; ++eb) {
        bf16x8 wf = *(const bf16x8*)(W + (size_t)(eb * 16 + b15) * 256 + kk * 32 + g * 8);
        acc[eb] = MFMA16(xf, wf, acc[eb], 0, 0, 0);
      }
    }
    float scale = (mat == 0) ? 0.0901684400555602f : 1.0f;  // log2(e)/16
    u16* dst = (mat == 0) ? Qs : Ks;
#pragma unroll
    for (int eb = 0; eb < 16; ++eb)
#pragma unroll
      for (int r = 0; r < 4; ++r)
        dst[(size_t)(base + g * 4 + r) * 256 + eb * 16 + b15] = f2bf(acc[eb][r] * scale);
  } else {
#pragma unroll
    for (int kk = 0; kk < 8; ++kk) {
      bf16x8 xf = *(const bf16x8*)(Xp + kk * 32 + g * 8);
#pragma unroll
      for (int eb = 0; eb < 16; ++eb) {
        bf16x8 wf = *(const bf16x8*)(W + (size_t)(eb * 16 + b15) * 256 + kk * 32 + g * 8);
        acc[eb] = MFMA16(wf, xf, acc[eb], 0, 0, 0);
      }
    }
    int sglob = base + b15;
    int b = sglob >> 12, sl = sglob & 4095;
#pragma unroll
    for (int eb = 0; eb < 16; ++eb)
#pragma unroll
      for (int r = 0; r < 4; ++r) {
        int e = eb * 16 + g * 4 + r;
        Vt[((size_t)(b * 256 + e) << 12) + sl] = f2bf(acc[eb][r]);
      }
  }
}

// ---------------- kernel 2: causal flash attention, 32x32 MFMA, balanced LPT jobs ----
// 512 jobs (128/batch), every CU exactly 2 blocks. Paired remainder jobs (4+16, 8+12)
// dispatched first; aligned 16-step kv-chunks (L2 sharing). K swz ^((row&15)<<4);
// V swz ^((e>>1&3)<<4). NT stores for pacc keep the XCD-pair L2 for Q/K/V.
// Defer-max guard is shuffle-free in the common path (identical trigger: __any spans
// both kv-halves; cross-half max only computed when rescale actually fires).
__global__ __launch_bounds__(256, 2) void attn_kernel(
    const u16* __restrict__ Qs, const u16* __restrict__ Ks_,
    const u16* __restrict__ Vt_, u16* __restrict__ pacc, float2* __restrict__ pml) {
  __shared__ u16 Kd[2][8192];   // [buf][32 kv][256 d] 512B rows
  __shared__ u16 Vd[2][8192];   // [buf][256 e][32 kv] 64B rows

  int bid = blockIdx.x;
  int xcd = bid & 7;
  int b = xcd >> 1;                           // batch -> XCD pair (L2 affinity)
  int j = ((bid >> 3) << 1) | (bid & 1);      // job 0..127 within batch
  int t0, c0, t1 = -1, c1 = 0;
  if (j < 16) {                               // paired remainder jobs (20 steps)
    int g = j & 7;
    if (j < 8) { t0 = 4 * g;     t1 = 4 * g + 3; }
    else       { t0 = 4 * g + 1; t1 = 4 * g + 2; }
    c0 = g; c1 = g;
  } else {                                    // singleton full-16 jobs
    int jj = j - 16;                          // 0..111
    int g = 1;
#pragma unroll
    for (int gg = 2; gg <= 7; ++gg) if (jj >= 2 * gg * (gg - 1)) g = gg;
    int r = jj - 2 * g * (g - 1);
    t0 = 4 * g + r / g; c0 = r % g;
  }

  int tid = threadIdx.x, w = tid >> 6, lane = tid & 63;
  int l31 = lane & 31, h = lane >> 5;

  // staging source offsets (inverse swizzle; LDS linear, source permuted)
  int Koff[4], Voff[4];
#pragma unroll
  for (int i = 0; i < 4; ++i) {
    int o = (w * 4 + i) * 1024 + lane * 16;
    int row = o >> 9;
    Koff[i] = row * 512 + ((o & 511) ^ ((row & 15) << 4));
    int e = o >> 6;
    Voff[i] = e * 8192 + ((o & 63) ^ (((e >> 1) & 3) << 4));
  }
  const char* Kgb = (const char*)(Ks_ + (size_t)b * 4096 * 256);
  const char* Vgb = (const char*)(Vt_ + (size_t)b * 1048576);
  char* KL = (char*)&Kd[0][0];
  char* VL = (char*)&Vd[0][0];

  auto stage = [&](int buf, int kt) {
    size_t kb = (size_t)kt * 32 * 512;
    size_t vb = (size_t)kt * 64;
#pragma unroll
    for (int i = 0; i < 4; ++i)
      gld16(Kgb + kb + Koff[i], KL + buf * 16384 + (w * 4 + i) * 1024);
#pragma unroll
    for (int i = 0; i < 4; ++i)
      gld16(Vgb + vb + Voff[i], VL + buf * 16384 + (w * 4 + i) * 1024);
  };

  auto process = [&](int tt, int c) {
    int g4 = tt >> 2;
    int uid = b * 144 + 2 * g4 * (g4 + 1) + (tt & 3) * (g4 + 1) + c;
    int qbase = tt * 128 + w * 32;
    int qrow = qbase + l31;
    int kt0 = 16 * c, kt_end = min(16 * c + 16, 4 * (tt + 1));

    const u16* Qrow = Qs + ((size_t)b * 4096 + qrow) * 256;
    bf16x8 qf[16];
#pragma unroll
    for (int kc = 0; kc < 16; ++kc)
      qf[kc] = *(const bf16x8*)(Qrow + kc * 16 + h * 8);

    f32x16 acc[8] = {};
    float m0 = -3e38f, l0 = 0.f;
    stage(0, kt0);
    int cur = 0;

    for (int kt = kt0; kt < kt_end; ++kt) {
      __syncthreads();                              // buf[cur] landed
      if (kt + 1 < kt_end) stage(cur ^ 1, kt + 1);  // fly during compute
      int kv0 = kt * 32;
      if (kv0 <= qbase + 31) {
        const char* Kc = KL + cur * 16384;
        const char* Vc = VL + cur * 16384;
        // --- QK^T: S^T[kv][q], two interleaved chains ---
        f32x16 sA = {}, sB = {};
        __builtin_amdgcn_s_setprio(1);
#pragma unroll
        for (int kc = 0; kc < 16; kc += 2) {
          bf16x8 k0 = *(const bf16x8*)(Kc + l31 * 512 + ((kc * 32 + h * 16) ^ ((l31 & 15) << 4)));
          bf16x8 k1 = *(const bf16x8*)(Kc + l31 * 512 + (((kc + 1) * 32 + h * 16) ^ ((l31 & 15) << 4)));
          sA = MFMA32(k0, qf[kc], sA, 0, 0, 0);
          sB = MFMA32(k1, qf[kc + 1], sB, 0, 0, 0);
        }
        __builtin_amdgcn_s_setprio(0);
        f32x16 s = sA + sB;
        if (kv0 + 31 > qbase) {  // diagonal: mask kv > qrow
#pragma unroll
          for (int r = 0; r < 16; ++r) {
            int kv = kv0 + (r & 3) + 8 * (r >> 2) + 4 * h;
            if (kv > qrow) s[r] = -3e38f;
          }
        }
        // --- softmax (base-2, defer-max THR=8), shuffle-free guard ---
        float a0 = fmaxf(fmaxf(s[0], s[1]), s[2]);
        float a1 = fmaxf(fmaxf(s[3], s[4]), s[5]);
        float a2 = fmaxf(fmaxf(s[6], s[7]), s[8]);
        float a3 = fmaxf(fmaxf(s[9], s[10]), s[11]);
        float a4 = fmaxf(fmaxf(s[12], s[13]), s[14]);
        float pmh = fmaxf(fmaxf(fmaxf(a0, a1), fmaxf(a2, a3)), fmaxf(a4, s[15]));
        // __any spans all 64 lanes -> detects overflow in either kv-half; cross-half
        // max only inside the rare rescale branch.
        if (__any(pmh > m0 + 8.f)) {
          float pm = fmaxf(pmh, __shfl_xor(pmh, 32));
          float mn = fmaxf(m0, pm);
          float sc = exp2f(m0 - mn);
          l0 *= sc;
#pragma unroll
          for (int et = 0; et < 8; ++et) acc[et] *= sc;
          m0 = mn;
        }
        float p[16];
#pragma unroll
        for (int r = 0; r < 16; ++r) p[r] = exp2f(s[r] - m0);
        // --- repack P -> PV B-operands (8 cvt_pk + 4 permlane32_swap) ---
        u32 w0 = cvtpk(p[0], p[1]),   w1 = cvtpk(p[2], p[3]);
        u32 w2 = cvtpk(p[4], p[5]),   w3 = cvtpk(p[6], p[7]);
        u32 w4 = cvtpk(p[8], p[9]),   w5 = cvtpk(p[10], p[11]);
        u32 w6 = cvtpk(p[12], p[13]), w7 = cvtpk(p[14], p[15]);
        pswap(w0, w2); pswap(w1, w3);   // -> B(kv 0..15):  [w0,w1,w2,w3]
        pswap(w4, w6); pswap(w5, w7);   // -> B(kv 16..31): [w4,w5,w6,w7]
        union { u32 uu[4]; bf16x8 vv; } pA, pB;
        pA.uu[0] = w0; pA.uu[1] = w1; pA.uu[2] = w2; pA.uu[3] = w3;
        pB.uu[0] = w4; pB.uu[1] = w5; pB.uu[2] = w6; pB.uu[3] = w7;
        // --- PV: O^T[e][q] += V^T x P^T ---
        __builtin_amdgcn_s_setprio(1);
#pragma unroll
        for (int et = 0; et < 8; ++et) {
          const char* vrow = Vc + (et * 32 + l31) * 64;
          int swz = ((l31 >> 1) & 3) << 4;
          bf16x8 vf0 = *(const bf16x8*)(vrow + ((h * 16) ^ swz));
          bf16x8 vf1 = *(const bf16x8*)(vrow + ((32 + h * 16) ^ swz));
          acc[et] = MFMA32(vf0, pA.vv, acc[et], 0, 0, 0);
          acc[et] = MFMA32(vf1, pB.vv, acc[et], 0, 0, 0);
        }
        __builtin_amdgcn_s_setprio(0);
        // l-sum tree after PV issue (off the S->PV critical chain)
        float q0 = (p[0] + p[1]) + (p[2] + p[3]);
        float q1 = (p[4] + p[5]) + (p[6] + p[7]);
        float q2 = (p[8] + p[9]) + (p[10] + p[11]);
        float q3 = (p[12] + p[13]) + (p[14] + p[15]);
        l0 += (q0 + q1) + (q2 + q3);
      }
      cur ^= 1;
    }

    // l across the two kv-half lanes
    l0 += __shfl_xor(l0, 32);

    // store partials (unnormalized acc bf16; m/l fp32); pacc NT -> keep L2 for Q/K/V
    u16* ppr = pacc + ((size_t)uid * 128 + w * 32 + l31) * 256;
#pragma unroll
    for (int et = 0; et < 8; ++et)
#pragma unroll
      for (int jj = 0; jj < 4; ++jj) {
        u32x2 o;
        o[0] = pk2(acc[et][4 * jj], acc[et][4 * jj + 1]);
        o[1] = pk2(acc[et][4 * jj + 2], acc[et][4 * jj + 3]);
        __builtin_nontemporal_store(o, (u32x2*)(ppr + et * 32 + 8 * jj + 4 * h));
      }
    if (h == 0) {
      float2 a; a.x = m0; a.y = l0;
      pml[(size_t)uid * 128 + w * 32 + l31] = a;
    }
  };

  process(t0, c0);
  if (t1 >= 0) {
    __syncthreads();   // all waves done reading LDS before re-staging
    process(t1, c1);
  }
}

// ---------------- kernel 3: combine partials ----------------
__global__ __launch_bounds__(256) void combine_kernel(
    const u16* __restrict__ pacc, const float2* __restrict__ pml,
    float* __restrict__ out) {
  int row = blockIdx.x * 4 + (threadIdx.x >> 6);
  int lane = threadIdx.x & 63;
  int b = row >> 12, r = row & 4095;
  int tt = r >> 7, rin = r & 127;
  int g4 = tt >> 2, nch = g4 + 1;
  int ubase = b * 144 + 2 * g4 * (g4 + 1) + (tt & 3) * (g4 + 1);
  float M = -3e38f;
  for (int cc = 0; cc < nch; ++cc)
    M = fmaxf(M, pml[(size_t)(ubase + cc) * 128 + rin].x);
  float L = 0.f, o0 = 0.f, o1 = 0.f, o2 = 0.f, o3 = 0.f;
  for (int cc = 0; cc < nch; ++cc) {
    float2 ml = pml[(size_t)(ubase + cc) * 128 + rin];
    float s = exp2f(ml.x - M);
    L += ml.y * s;
    u32x2 a = __builtin_nontemporal_load(
        (const u32x2*)(pacc + ((size_t)(ubase + cc) * 128 + rin) * 256 + lane * 4));
    o0 += s * bf2f(a[0] & 0xffffu); o1 += s * bf2f(a[0] >> 16);
    o2 += s * bf2f(a[1] & 0xffffu); o3 += s * bf2f(a[1] >> 16);
  }
  float inv = 1.f / L;
  f32x4 res = {o0 * inv, o1 * inv, o2 * inv, o3 * inv};
  __builtin_nontemporal_store(res, (f32x4*)(out + (size_t)row * 256 + lane * 4));
}

// ---------------- launch ----------------
extern "C" void kernel_launch(void* const* d_in, const int* in_sizes, int n_in,
                              void* d_out, int out_size, void* d_ws, size_t ws_size,
                              hipStream_t stream) {
  const float* x = (const float*)d_in[0];
  const float* wq = (const float*)d_in[1];
  const float* wk = (const float*)d_in[2];
  const float* wv = (const float*)d_in[3];
  char* ws = (char*)d_ws;
  u16* xbf = (u16*)(ws);                    // 8 MB
  u16* wbf = (u16*)(ws + 8388608);          // 384 KB
  u16* Qs  = (u16*)(ws + 9437184);          // 8 MB (pre-scaled)
  u16* Ks  = (u16*)(ws + 17825792);         // 8 MB
  u16* Vt  = (u16*)(ws + 26214400);         // 8 MB [b][e][s]
  u16* pacc = (u16*)(ws + 34603008);        // 36 MB partial acc (bf16)
  float2* pml = (float2*)(ws + 72351744);   // 576 KB partial m/l
  float* out = (float*)d_out;

  hipLaunchKernelGGL(cvt_kernel, dim3(4288), dim3(256), 0, stream, x, wq, wk, wv, xbf, wbf);
  hipLaunchKernelGGL(proj_kernel, dim3(256, 3), dim3(256), 0, stream, xbf, wbf, Qs, Ks, Vt);
  hipLaunchKernelGGL(attn_kernel, dim3(512), dim3(256), 0, stream, Qs, Ks, Vt, pacc, pml);
  hipLaunchKernelGGL(combine_kernel, dim3(4096), dim3(256), 0, stream, pacc, pml, out);
}

// Round 10
// 158.307 us; speedup vs baseline: 1.4032x; 1.4032x over previous
//
#include <hip/hip_runtime.h>

typedef unsigned short u16;
typedef unsigned int u32;
typedef __attribute__((ext_vector_type(8))) short bf16x8;
typedef __attribute__((ext_vector_type(4))) float f32x4;
typedef __attribute__((ext_vector_type(16))) float f32x16;
typedef __attribute__((ext_vector_type(2))) unsigned int u32x2;

#define MFMA16 __builtin_amdgcn_mfma_f32_16x16x32_bf16
#define MFMA32 __builtin_amdgcn_mfma_f32_32x32x16_bf16

__device__ __forceinline__ u16 f2bf(float f) {
  u32 u = __builtin_bit_cast(u32, f);
  u = u + 0x7FFFu + ((u >> 16) & 1u);
  return (u16)(u >> 16);
}
__device__ __forceinline__ u32 pk2(float lo, float hi) {
  return (u32)f2bf(lo) | ((u32)f2bf(hi) << 16);
}
__device__ __forceinline__ float bf2f(u32 x) {
  return __builtin_bit_cast(float, x << 16);
}
__device__ __forceinline__ u32 cvtpk(float lo, float hi) {
  u32 r;
  asm("v_cvt_pk_bf16_f32 %0, %1, %2" : "=v"(r) : "v"(lo), "v"(hi));
  return r;
}
// v_permlane32_swap_b32 a, b : new a = {a.lo, b.lo}, new b = {a.hi, b.hi}
// ONLY safe with genuinely distinct source registers (R5-proven in repack).
// R6 LESSON: self-swap emulation of shfl_xor(32) broke. R9 LESSON: NT stores on
// row-scattered 8B writes bypass L2 write-coalescing -> ~3x HBM write amplification.
__device__ __forceinline__ void pswap(u32& x, u32& y) {
  asm("v_permlane32_swap_b32 %0, %1" : "+v"(x), "+v"(y));
}
__device__ __forceinline__ void gld16(const void* gp, void* lp) {
  __builtin_amdgcn_global_load_lds((const __attribute__((address_space(1))) u32*)gp,
                                   (__attribute__((address_space(3))) u32*)lp, 16, 0, 0);
}

// ---------------- kernel 0: fp32 -> bf16 convert (x, Wq|Wk|Wv) ----------------
__global__ __launch_bounds__(256) void cvt_kernel(
    const float* __restrict__ x, const float* __restrict__ wq,
    const float* __restrict__ wk, const float* __restrict__ wv,
    u16* __restrict__ xbf, u16* __restrict__ wbf) {
  int idx = blockIdx.x * 256 + threadIdx.x;
  if (idx < 1048576) {
    float4 v = ((const float4*)x)[idx];
    uint2 u; u.x = pk2(v.x, v.y); u.y = pk2(v.z, v.w);
    ((uint2*)xbf)[idx] = u;
  } else {
    int j = idx - 1048576;
    const float* W = (j < 16384) ? wq : (j < 32768) ? wk : wv;
    int k = j & 16383;
    float4 v = ((const float4*)W)[k];
    uint2 u; u.x = pk2(v.x, v.y); u.y = pk2(v.z, v.w);
    ((uint2*)wbf)[j] = u;
  }
}

// ---------------- kernel 1: QKV projection ----------------
// mat 0: Qs[s][e] = (x @ Wq^T) * (log2(e)/16)
// mat 1: Ks[s][e] =  x @ Wk^T
// mat 2: Vt[e][s] =  (x @ Wv^T)^T
__global__ __launch_bounds__(256, 2) void proj_kernel(
    const u16* __restrict__ xbf, const u16* __restrict__ wbf,
    u16* __restrict__ Qs, u16* __restrict__ Ks, u16* __restrict__ Vt) {
  int tile = blockIdx.x, mat = blockIdx.y;
  int tid = threadIdx.x, w = tid >> 6, lane = tid & 63, b15 = lane & 15, g = lane >> 4;
  int base = tile * 64 + w * 16;
  const u16* W = wbf + mat * 65536;
  const u16* Xp = xbf + (size_t)(base + b15) * 256;
  f32x4 acc[16] = {};
  if (mat < 2) {
#pragma unroll
    for (int kk = 0; kk < 8; ++kk) {
      bf16x8 xf = *(const bf16x8*)(Xp + kk * 32 + g * 8);
#pragma unroll
      for (int eb = 0; eb < 16; ++eb) {
        bf16x8 wf = *(const bf16x8*)(W + (size_t)(eb * 16 + b15) * 256 + kk * 32 + g * 8);
        acc[eb] = MFMA16(xf, wf, acc[eb], 0, 0, 0);
      }
    }
    float scale = (mat == 0) ? 0.0901684400555602f : 1.0f;  // log2(e)/16
    u16* dst = (mat == 0) ? Qs : Ks;
#pragma unroll
    for (int eb = 0; eb < 16; ++eb)
#pragma unroll
      for (int r = 0; r < 4; ++r)
        dst[(size_t)(base + g * 4 + r) * 256 + eb * 16 + b15] = f2bf(acc[eb][r] * scale);
  } else {
#pragma unroll
    for (int kk = 0; kk < 8; ++kk) {
      bf16x8 xf = *(const bf16x8*)(Xp + kk * 32 + g * 8);
#pragma unroll
      for (int eb = 0; eb < 16; ++eb) {
        bf16x8 wf = *(const bf16x8*)(W + (size_t)(eb * 16 + b15) * 256 + kk * 32 + g * 8);
        acc[eb] = MFMA16(wf, xf, acc[eb], 0, 0, 0);
      }
    }
    int sglob = base + b15;
    int b = sglob >> 12, sl = sglob & 4095;
#pragma unroll
    for (int eb = 0; eb < 16; ++eb)
#pragma unroll
      for (int r = 0; r < 4; ++r) {
        int e = eb * 16 + g * 4 + r;
        Vt[((size_t)(b * 256 + e) << 12) + sl] = f2bf(acc[eb][r]);
      }
  }
}

// ---------------- kernel 2: causal flash attention, 32x32 MFMA, balanced LPT jobs ----
// 512 jobs (128/batch), every CU exactly 2 blocks. Paired remainder jobs (4+16, 8+12)
// dispatched first; aligned 16-step kv-chunks (L2 sharing). K swz ^((row&15)<<4);
// V swz ^((e>>1&3)<<4). Plain (L2-cached) pacc stores — NT regressed 3x (R9).
__global__ __launch_bounds__(256, 2) void attn_kernel(
    const u16* __restrict__ Qs, const u16* __restrict__ Ks_,
    const u16* __restrict__ Vt_, u16* __restrict__ pacc, float2* __restrict__ pml) {
  __shared__ u16 Kd[2][8192];   // [buf][32 kv][256 d] 512B rows
  __shared__ u16 Vd[2][8192];   // [buf][256 e][32 kv] 64B rows

  int bid = blockIdx.x;
  int xcd = bid & 7;
  int b = xcd >> 1;                           // batch -> XCD pair (L2 affinity)
  int j = ((bid >> 3) << 1) | (bid & 1);      // job 0..127 within batch
  int t0, c0, t1 = -1, c1 = 0;
  if (j < 16) {                               // paired remainder jobs (20 steps)
    int g = j & 7;
    if (j < 8) { t0 = 4 * g;     t1 = 4 * g + 3; }
    else       { t0 = 4 * g + 1; t1 = 4 * g + 2; }
    c0 = g; c1 = g;
  } else {                                    // singleton full-16 jobs
    int jj = j - 16;                          // 0..111
    int g = 1;
#pragma unroll
    for (int gg = 2; gg <= 7; ++gg) if (jj >= 2 * gg * (gg - 1)) g = gg;
    int r = jj - 2 * g * (g - 1);
    t0 = 4 * g + r / g; c0 = r % g;
  }

  int tid = threadIdx.x, w = tid >> 6, lane = tid & 63;
  int l31 = lane & 31, h = lane >> 5;

  // staging source offsets (inverse swizzle; LDS linear, source permuted)
  int Koff[4], Voff[4];
#pragma unroll
  for (int i = 0; i < 4; ++i) {
    int o = (w * 4 + i) * 1024 + lane * 16;
    int row = o >> 9;
    Koff[i] = row * 512 + ((o & 511) ^ ((row & 15) << 4));
    int e = o >> 6;
    Voff[i] = e * 8192 + ((o & 63) ^ (((e >> 1) & 3) << 4));
  }
  const char* Kgb = (const char*)(Ks_ + (size_t)b * 4096 * 256);
  const char* Vgb = (const char*)(Vt_ + (size_t)b * 1048576);
  char* KL = (char*)&Kd[0][0];
  char* VL = (char*)&Vd[0][0];

  auto stage = [&](int buf, int kt) {
    size_t kb = (size_t)kt * 32 * 512;
    size_t vb = (size_t)kt * 64;
#pragma unroll
    for (int i = 0; i < 4; ++i)
      gld16(Kgb + kb + Koff[i], KL + buf * 16384 + (w * 4 + i) * 1024);
#pragma unroll
    for (int i = 0; i < 4; ++i)
      gld16(Vgb + vb + Voff[i], VL + buf * 16384 + (w * 4 + i) * 1024);
  };

  auto process = [&](int tt, int c) {
    int g4 = tt >> 2;
    int uid = b * 144 + 2 * g4 * (g4 + 1) + (tt & 3) * (g4 + 1) + c;
    int qbase = tt * 128 + w * 32;
    int qrow = qbase + l31;
    int kt0 = 16 * c, kt_end = min(16 * c + 16, 4 * (tt + 1));

    const u16* Qrow = Qs + ((size_t)b * 4096 + qrow) * 256;
    bf16x8 qf[16];
#pragma unroll
    for (int kc = 0; kc < 16; ++kc)
      qf[kc] = *(const bf16x8*)(Qrow + kc * 16 + h * 8);

    f32x16 acc[8] = {};
    float m0 = -3e38f, l0 = 0.f;
    stage(0, kt0);
    int cur = 0;

    for (int kt = kt0; kt < kt_end; ++kt) {
      __syncthreads();                              // buf[cur] landed
      if (kt + 1 < kt_end) stage(cur ^ 1, kt + 1);  // fly during compute
      int kv0 = kt * 32;
      if (kv0 <= qbase + 31) {
        const char* Kc = KL + cur * 16384;
        const char* Vc = VL + cur * 16384;
        // --- QK^T: S^T[kv][q], two interleaved chains ---
        f32x16 sA = {}, sB = {};
        __builtin_amdgcn_s_setprio(1);
#pragma unroll
        for (int kc = 0; kc < 16; kc += 2) {
          bf16x8 k0 = *(const bf16x8*)(Kc + l31 * 512 + ((kc * 32 + h * 16) ^ ((l31 & 15) << 4)));
          bf16x8 k1 = *(const bf16x8*)(Kc + l31 * 512 + (((kc + 1) * 32 + h * 16) ^ ((l31 & 15) << 4)));
          sA = MFMA32(k0, qf[kc], sA, 0, 0, 0);
          sB = MFMA32(k1, qf[kc + 1], sB, 0, 0, 0);
        }
        __builtin_amdgcn_s_setprio(0);
        f32x16 s = sA + sB;
        if (kv0 + 31 > qbase) {  // diagonal: mask kv > qrow
#pragma unroll
          for (int r = 0; r < 16; ++r) {
            int kv = kv0 + (r & 3) + 8 * (r >> 2) + 4 * h;
            if (kv > qrow) s[r] = -3e38f;
          }
        }
        // --- softmax (base-2, defer-max THR=8), shuffle-free guard ---
        float a0 = fmaxf(fmaxf(s[0], s[1]), s[2]);
        float a1 = fmaxf(fmaxf(s[3], s[4]), s[5]);
        float a2 = fmaxf(fmaxf(s[6], s[7]), s[8]);
        float a3 = fmaxf(fmaxf(s[9], s[10]), s[11]);
        float a4 = fmaxf(fmaxf(s[12], s[13]), s[14]);
        float pmh = fmaxf(fmaxf(fmaxf(a0, a1), fmaxf(a2, a3)), fmaxf(a4, s[15]));
        // __any spans all 64 lanes -> detects overflow in either kv-half; cross-half
        // max only inside the rare rescale branch.
        if (__any(pmh > m0 + 8.f)) {
          float pm = fmaxf(pmh, __shfl_xor(pmh, 32));
          float mn = fmaxf(m0, pm);
          float sc = exp2f(m0 - mn);
          l0 *= sc;
#pragma unroll
          for (int et = 0; et < 8; ++et) acc[et] *= sc;
          m0 = mn;
        }
        float p[16];
#pragma unroll
        for (int r = 0; r < 16; ++r) p[r] = exp2f(s[r] - m0);
        // --- repack P -> PV B-operands (8 cvt_pk + 4 permlane32_swap) ---
        u32 w0 = cvtpk(p[0], p[1]),   w1 = cvtpk(p[2], p[3]);
        u32 w2 = cvtpk(p[4], p[5]),   w3 = cvtpk(p[6], p[7]);
        u32 w4 = cvtpk(p[8], p[9]),   w5 = cvtpk(p[10], p[11]);
        u32 w6 = cvtpk(p[12], p[13]), w7 = cvtpk(p[14], p[15]);
        pswap(w0, w2); pswap(w1, w3);   // -> B(kv 0..15):  [w0,w1,w2,w3]
        pswap(w4, w6); pswap(w5, w7);   // -> B(kv 16..31): [w4,w5,w6,w7]
        union { u32 uu[4]; bf16x8 vv; } pA, pB;
        pA.uu[0] = w0; pA.uu[1] = w1; pA.uu[2] = w2; pA.uu[3] = w3;
        pB.uu[0] = w4; pB.uu[1] = w5; pB.uu[2] = w6; pB.uu[3] = w7;
        // --- PV: O^T[e][q] += V^T x P^T ---
        __builtin_amdgcn_s_setprio(1);
#pragma unroll
        for (int et = 0; et < 8; ++et) {
          const char* vrow = Vc + (et * 32 + l31) * 64;
          int swz = ((l31 >> 1) & 3) << 4;
          bf16x8 vf0 = *(const bf16x8*)(vrow + ((h * 16) ^ swz));
          bf16x8 vf1 = *(const bf16x8*)(vrow + ((32 + h * 16) ^ swz));
          acc[et] = MFMA32(vf0, pA.vv, acc[et], 0, 0, 0);
          acc[et] = MFMA32(vf1, pB.vv, acc[et], 0, 0, 0);
        }
        __builtin_amdgcn_s_setprio(0);
        // l-sum tree after PV issue (off the S->PV critical chain)
        float q0 = (p[0] + p[1]) + (p[2] + p[3]);
        float q1 = (p[4] + p[5]) + (p[6] + p[7]);
        float q2 = (p[8] + p[9]) + (p[10] + p[11]);
        float q3 = (p[12] + p[13]) + (p[14] + p[15]);
        l0 += (q0 + q1) + (q2 + q3);
      }
      cur ^= 1;
    }

    // l across the two kv-half lanes
    l0 += __shfl_xor(l0, 32);

    // store partials (unnormalized acc bf16; m/l fp32) — plain stores, L2 coalesces
    u16* ppr = pacc + ((size_t)uid * 128 + w * 32 + l31) * 256;
#pragma unroll
    for (int et = 0; et < 8; ++et)
#pragma unroll
      for (int jj = 0; jj < 4; ++jj) {
        u32x2 o;
        o[0] = pk2(acc[et][4 * jj], acc[et][4 * jj + 1]);
        o[1] = pk2(acc[et][4 * jj + 2], acc[et][4 * jj + 3]);
        *(u32x2*)(ppr + et * 32 + 8 * jj + 4 * h) = o;
      }
    if (h == 0) {
      float2 a; a.x = m0; a.y = l0;
      pml[(size_t)uid * 128 + w * 32 + l31] = a;
    }
  };

  process(t0, c0);
  if (t1 >= 0) {
    __syncthreads();   // all waves done reading LDS before re-staging
    process(t1, c1);
  }
}

// ---------------- kernel 3: combine partials ----------------
__global__ __launch_bounds__(256) void combine_kernel(
    const u16* __restrict__ pacc, const float2* __restrict__ pml,
    float* __restrict__ out) {
  int row = blockIdx.x * 4 + (threadIdx.x >> 6);
  int lane = threadIdx.x & 63;
  int b = row >> 12, r = row & 4095;
  int tt = r >> 7, rin = r & 127;
  int g4 = tt >> 2, nch = g4 + 1;
  int ubase = b * 144 + 2 * g4 * (g4 + 1) + (tt & 3) * (g4 + 1);
  float M = -3e38f;
  for (int cc = 0; cc < nch; ++cc)
    M = fmaxf(M, pml[(size_t)(ubase + cc) * 128 + rin].x);
  float L = 0.f, o0 = 0.f, o1 = 0.f, o2 = 0.f, o3 = 0.f;
  for (int cc = 0; cc < nch; ++cc) {
    float2 ml = pml[(size_t)(ubase + cc) * 128 + rin];
    float s = exp2f(ml.x - M);
    L += ml.y * s;
    u32x2 a = *(const u32x2*)(pacc + ((size_t)(ubase + cc) * 128 + rin) * 256 + lane * 4);
    o0 += s * bf2f(a[0] & 0xffffu); o1 += s * bf2f(a[0] >> 16);
    o2 += s * bf2f(a[1] & 0xffffu); o3 += s * bf2f(a[1] >> 16);
  }
  float inv = 1.f / L;
  f32x4 res = {o0 * inv, o1 * inv, o2 * inv, o3 * inv};
  *(f32x4*)(out + (size_t)row * 256 + lane * 4) = res;
}

// ---------------- launch ----------------
extern "C" void kernel_launch(void* const* d_in, const int* in_sizes, int n_in,
                              void* d_out, int out_size, void* d_ws, size_t ws_size,
                              hipStream_t stream) {
  const float* x = (const float*)d_in[0];
  const float* wq = (const float*)d_in[1];
  const float* wk = (const float*)d_in[2];
  const float* wv = (const float*)d_in[3];
  char* ws = (char*)d_ws;
  u16* xbf = (u16*)(ws);                    // 8 MB
  u16* wbf = (u16*)(ws + 8388608);          // 384 KB
  u16* Qs  = (u16*)(ws + 9437184);          // 8 MB (pre-scaled)
  u16* Ks  = (u16*)(ws + 17825792);         // 8 MB
  u16* Vt  = (u16*)(ws + 26214400);         // 8 MB [b][e][s]
  u16* pacc = (u16*)(ws + 34603008);        // 36 MB partial acc (bf16)
  float2* pml = (float2*)(ws + 72351744);   // 576 KB partial m/l
  float* out = (float*)d_out;

  hipLaunchKernelGGL(cvt_kernel, dim3(4288), dim3(256), 0, stream, x, wq, wk, wv, xbf, wbf);
  hipLaunchKernelGGL(proj_kernel, dim3(256, 3), dim3(256), 0, stream, xbf, wbf, Qs, Ks, Vt);
  hipLaunchKernelGGL(attn_kernel, dim3(512), dim3(256), 0, stream, Qs, Ks, Vt, pacc, pml);
  hipLaunchKernelGGL(combine_kernel, dim3(4096), dim3(256), 0, stream, pacc, pml, out);
}